// Round 1
// 55.129 us; speedup vs baseline: 1.1028x; 1.1028x over previous
//
#include <hip/hip_runtime.h>

// RankLoss: loss = -mean_b( 1 / (sum_j sigmoid(x[b,j] - x[b,0]) + 0.5) )
// Only row i=0 of the pairwise matrix is consumed: O(B*N) = 32*2048 sigmoids.
//
// v2: parallelize across CUs. The previous version ran 16 waves on ONE CU,
// serializing ~8k cycles/SIMD of transcendental work (64 exp + 64 div per
// lane) plus 256 KB of L2 reads through one CU's port (~5-10 us wall).
// Now: kernel 1 = 32 blocks (one per row b, 1 wave each) -> rr[b] in d_ws.
//      kernel 2 = 1 block, reduces the 32 partials -> out.
// d_ws is re-poisoned by the harness each iteration, but we write our 32
// floats before reading them (stream-ordered), so no dependence on its
// initial contents. Inter-kernel visibility is guaranteed by same-stream
// dispatch ordering (runtime flushes/invalidates L2 between nodes).

#define RL_B 32
#define RL_N 2048

__device__ __forceinline__ float sig(float d) {
    return 1.0f / (1.0f + __expf(-d));
}

__global__ __launch_bounds__(64) void RankLoss_73959336837390_rows(
    const float* __restrict__ x, float* __restrict__ partial) {
    const int b    = blockIdx.x;    // 0..31, one row pair-sum per block
    const int lane = threadIdx.x;   // 0..63, single wave

    const float* __restrict__ row = x + b * RL_N;
    const float4* __restrict__ r4 = (const float4*)row;

    // Broadcast pivot (same address across the wave -> one transaction).
    const float x0 = row[0];

    // 2048 floats = 512 float4 over 64 lanes: 8 per lane, coalesced
    // (lane + 64k). Issue all loads before any compute.
    float4 v[8];
    #pragma unroll
    for (int k = 0; k < 8; ++k) v[k] = r4[lane + (k << 6)];

    float s = 0.0f;
    #pragma unroll
    for (int k = 0; k < 8; ++k) {
        s += sig(v[k].x - x0) + sig(v[k].y - x0)
           + sig(v[k].z - x0) + sig(v[k].w - x0);
    }

    // 64-lane butterfly reduction.
    #pragma unroll
    for (int off = 32; off > 0; off >>= 1) s += __shfl_xor(s, off, 64);

    if (lane == 0) partial[b] = 1.0f / (s + 0.5f);
}

__global__ __launch_bounds__(64) void RankLoss_73959336837390_reduce(
    const float* __restrict__ partial, float* __restrict__ out) {
    const int lane = threadIdx.x;   // single wave
    float v = (lane < RL_B) ? partial[lane] : 0.0f;
    #pragma unroll
    for (int off = 32; off > 0; off >>= 1) v += __shfl_xor(v, off, 64);
    if (lane == 0) *out = -v / (float)RL_B;
}

extern "C" void kernel_launch(void* const* d_in, const int* in_sizes, int n_in,
                              void* d_out, int out_size, void* d_ws, size_t ws_size,
                              hipStream_t stream) {
    const float* x = (const float*)d_in[0];
    float* out     = (float*)d_out;
    float* partial = (float*)d_ws;   // 32 floats; overwritten before read

    RankLoss_73959336837390_rows<<<RL_B, 64, 0, stream>>>(x, partial);
    RankLoss_73959336837390_reduce<<<1, 64, 0, stream>>>(partial, out);
}